// Round 5
// baseline (321.989 us; speedup 1.0000x reference)
//
#include <hip/hip_runtime.h>
#include <math.h>

#define BB 64
#define TT 2048
#define RNN 1024
#define EMB 512
#define ATTN 128
#define NF 32
#define KS 31
#define PADW 15

#define CHW 16            // t per wave
#define NCH (TT / CHW)    // 128 chunks per b
#define BLK_T 64          // t per block (4 waves)

__device__ __forceinline__ float fast_tanh(float x) {
    float ax = fabsf(x);
    float e = __expf(-2.f * ax);
    float r = (1.f - e) * __builtin_amdgcn_rcpf(1.f + e);
    return copysignf(r, x);
}

// ---------------------------------------------------------------------------
// Kernel 1: pq[b][a] = sum_r h[b][r] * Wq[a][r]
// ---------------------------------------------------------------------------
__global__ __launch_bounds__(256) void pq_kernel(const float* __restrict__ h,
                                                 const float* __restrict__ Wq,
                                                 float* __restrict__ pq) {
    int b = blockIdx.x >> 2;
    int q = blockIdx.x & 3;
    __shared__ float s_h[RNN];
    for (int i = threadIdx.x; i < RNN; i += 256) s_h[i] = h[b * RNN + i];
    __syncthreads();

    int wave = threadIdx.x >> 6;
    int lane = threadIdx.x & 63;
#pragma unroll 2
    for (int j = 0; j < 8; ++j) {
        int a = q * 32 + wave * 8 + j;
        const float4* wq4 = (const float4*)(Wq + (size_t)a * RNN);
        float acc = 0.f;
#pragma unroll
        for (int i = 0; i < 4; ++i) {
            float4 w4 = wq4[lane + 64 * i];
            float4 h4 = *(const float4*)(s_h + 4 * (lane + 64 * i));
            acc += w4.x * h4.x + w4.y * h4.y + w4.z * h4.z + w4.w * h4.w;
        }
#pragma unroll
        for (int off = 32; off > 0; off >>= 1) acc += __shfl_xor(acc, off, 64);
        if (lane == 0) pq[b * ATTN + a] = acc;
    }
}

// ---------------------------------------------------------------------------
// Kernel 2 (fused, one barrier): block = 64 t (4 waves), wave owns 16 t.
//   [stage awc + block conv] -> barrier -> per wave, no further sync:
//   energies (batched butterfly) -> in-register chunk softmax -> partial ctx
// grid = B * 32 = 2048, block = 256
// ---------------------------------------------------------------------------
__global__ __launch_bounds__(256, 4) void fused_kernel(
    const float* __restrict__ pm,     // [B][T][ATTN]
    const float* __restrict__ awc,    // [B][2][T]
    const float* __restrict__ mem,    // [B][T][EMB]
    const unsigned char* __restrict__ mask,  // [B][T]
    const float* __restrict__ pq,     // [B][ATTN]
    const float* __restrict__ Wconv,  // [NF][2][KS]
    const float* __restrict__ Wloc,   // [ATTN][NF]
    const float* __restrict__ Wv,     // [ATTN]
    float* __restrict__ wp,           // [B][T] unnormalized exp
    float* __restrict__ ms,           // [B][NCH][2] (m, s)
    float* __restrict__ cp)           // [B][NCH][EMB] partial ctx
{
    int b = blockIdx.x >> 5;
    int chg = blockIdx.x & 31;
    int t0b = chg * BLK_T;
    int tid = threadIdx.x;
    int w = tid >> 6;
    int lane = tid & 63;
    int ch = chg * 4 + w;        // wave's global chunk
    int t0w = ch * CHW;          // wave's first t

    __shared__ float s_awc[2][BLK_T + 2 * PADW + 2];  // 2 x 96
    __shared__ float s_conv[BLK_T][36];

    // ---- stage awc window for the block's 64 t ----
    for (int i = tid; i < 2 * (BLK_T + 2 * PADW); i += 256) {
        int c = i / (BLK_T + 2 * PADW);
        int j = i % (BLK_T + 2 * PADW);
        int tg = t0b - PADW + j;
        s_awc[c][j] = (tg >= 0 && tg < TT) ? awc[((size_t)b * 2 + c) * TT + tg] : 0.f;
    }
    __syncthreads();

    // ---- block-cooperative conv: t = tid&63, wave-uniform filter group ----
    {
        int t = tid & 63;
        float aw[2][KS];
#pragma unroll
        for (int c = 0; c < 2; ++c)
#pragma unroll
            for (int k = 0; k < KS; ++k) aw[c][k] = s_awc[c][t + k];
#pragma unroll
        for (int ff = 0; ff < 8; ++ff) {
            int f = w * 8 + ff;  // wave-uniform -> scalar Wconv loads
            float acc = 0.f;
#pragma unroll
            for (int c = 0; c < 2; ++c)
#pragma unroll
                for (int k = 0; k < KS; ++k)
                    acc += aw[c][k] * Wconv[(f * 2 + c) * KS + k];
            s_conv[t][f] = acc;
        }
    }
    __syncthreads();   // the ONLY barrier; all below is wave-autonomous

    // ---- energies: lane owns attn dims (lane, lane+64), 16 t in regs ----
    float wl0[NF], wl1[NF];
#pragma unroll
    for (int f = 0; f < NF; ++f) {
        wl0[f] = Wloc[lane * NF + f];
        wl1[f] = Wloc[(lane + 64) * NF + f];
    }
    float pq0 = pq[b * ATTN + lane], pq1 = pq[b * ATTN + lane + 64];
    float wv0 = Wv[lane], wv1 = Wv[lane + 64];

    float e[CHW];
#pragma unroll
    for (int h = 0; h < 2; ++h) {
        float pA[8], pB[8];
#pragma unroll
        for (int i = 0; i < 8; ++i) {  // issue 16 loads up front
            const float* r = pm + ((size_t)b * TT + t0w + h * 8 + i) * ATTN;
            pA[i] = r[lane];
            pB[i] = r[lane + 64];
        }
#pragma unroll
        for (int i = 0; i < 8; ++i) {
            int tl = w * CHW + h * 8 + i;   // row in s_conv
            float v0 = pq0 + pA[i], v1 = pq1 + pB[i];
            const float4* cv4 = (const float4*)&s_conv[tl][0];  // broadcast
#pragma unroll
            for (int f4 = 0; f4 < 8; ++f4) {
                float4 cv = cv4[f4];
                v0 += cv.x * wl0[f4 * 4 + 0] + cv.y * wl0[f4 * 4 + 1] +
                      cv.z * wl0[f4 * 4 + 2] + cv.w * wl0[f4 * 4 + 3];
                v1 += cv.x * wl1[f4 * 4 + 0] + cv.y * wl1[f4 * 4 + 1] +
                      cv.z * wl1[f4 * 4 + 2] + cv.w * wl1[f4 * 4 + 3];
            }
            e[h * 8 + i] = wv0 * fast_tanh(v0) + wv1 * fast_tanh(v1);
        }
    }

    // batched butterfly: 6 rounds x 16 independent shuffles
#pragma unroll
    for (int off = 32; off > 0; off >>= 1)
#pragma unroll
        for (int i = 0; i < CHW; ++i) e[i] += __shfl_xor(e[i], off, 64);
    // now every lane holds all 16 full energies

    // mask (broadcast byte loads, applied uniformly in every lane)
    {
        const unsigned int* mk4 = (const unsigned int*)(mask + (size_t)b * TT + t0w);
#pragma unroll
        for (int q = 0; q < 4; ++q) {
            unsigned int mword = mk4[q];
#pragma unroll
            for (int j = 0; j < 4; ++j)
                if ((mword >> (8 * j)) & 0xff) e[q * 4 + j] = -1e30f;
        }
    }

    // in-register chunk softmax (redundant per lane; zero shuffles/LDS)
    float m = e[0];
#pragma unroll
    for (int i = 1; i < CHW; ++i) m = fmaxf(m, e[i]);
    float p[CHW], s = 0.f;
#pragma unroll
    for (int i = 0; i < CHW; ++i) {
        p[i] = __expf(e[i] - m);
        s += p[i];
    }
    if (lane == 0) {
        ms[((size_t)b * NCH + ch) * 2 + 0] = m;
        ms[((size_t)b * NCH + ch) * 2 + 1] = s;
    }
    // wp: lane i (<16) stores p[i] via cndmask select chain
    {
        float pv = p[0];
#pragma unroll
        for (int i = 1; i < CHW; ++i)
            if (lane == i) pv = p[i];
        if (lane < CHW) wp[(size_t)b * TT + t0w + lane] = pv;
    }

    // ---- partial ctx over wave's 16 t: lane owns float4 cols l, l+64 ----
    float4 a0 = {0.f, 0.f, 0.f, 0.f}, a1 = {0.f, 0.f, 0.f, 0.f};
    const float4* m4 = (const float4*)(mem + ((size_t)b * TT + t0w) * EMB);
#pragma unroll
    for (int i = 0; i < CHW; ++i) {
        float pi = p[i];
        float4 v0 = m4[(size_t)i * (EMB / 4) + lane];
        float4 v1 = m4[(size_t)i * (EMB / 4) + 64 + lane];
        a0.x += pi * v0.x; a0.y += pi * v0.y; a0.z += pi * v0.z; a0.w += pi * v0.w;
        a1.x += pi * v1.x; a1.y += pi * v1.y; a1.z += pi * v1.z; a1.w += pi * v1.w;
    }
    float4* cp4 = (float4*)(cp + ((size_t)b * NCH + ch) * EMB);
    cp4[lane] = a0;
    cp4[64 + lane] = a1;
}

// ---------------------------------------------------------------------------
// Kernel 3: combine. grid = B, block = 256.
// ---------------------------------------------------------------------------
__global__ __launch_bounds__(256) void combine_kernel(
    const float* __restrict__ wp, const float* __restrict__ ms,
    const float* __restrict__ cp, float* __restrict__ ctx,
    float* __restrict__ wts) {
    int b = blockIdx.x;
    int tid = threadIdx.x;
    __shared__ float s_m[NCH], s_s[NCH], s_scale[NCH];
    if (tid < NCH) {
        s_m[tid] = ms[((size_t)b * NCH + tid) * 2 + 0];
        s_s[tid] = ms[((size_t)b * NCH + tid) * 2 + 1];
    }
    __syncthreads();
    float M = -1e30f;
#pragma unroll 8
    for (int c = 0; c < NCH; ++c) M = fmaxf(M, s_m[c]);
    float S = 0.f;
#pragma unroll 8
    for (int c = 0; c < NCH; ++c) S += s_s[c] * __expf(s_m[c] - M);
    float invS = 1.f / S;
    if (tid < NCH) s_scale[tid] = __expf(s_m[tid] - M) * invS;
    __syncthreads();

    // ctx: 256 threads x float2 covers EMB=512
    {
        float2 acc = {0.f, 0.f};
        const float2* cp2 = (const float2*)(cp + (size_t)b * NCH * EMB);
#pragma unroll 4
        for (int c = 0; c < NCH; ++c) {
            float sc = s_scale[c];
            float2 v = cp2[(size_t)c * (EMB / 2) + tid];
            acc.x += sc * v.x;
            acc.y += sc * v.y;
        }
        ((float2*)(ctx + (size_t)b * EMB))[tid] = acc;
    }
#pragma unroll
    for (int i = 0; i < 8; ++i) {
        int t = i * 256 + tid;
        wts[(size_t)b * TT + t] = wp[(size_t)b * TT + t] * s_scale[t >> 4];
    }
}

// ---------------------------------------------------------------------------
extern "C" void kernel_launch(void* const* d_in, const int* in_sizes, int n_in,
                              void* d_out, int out_size, void* d_ws, size_t ws_size,
                              hipStream_t stream) {
    const float* h    = (const float*)d_in[0];
    const float* mem  = (const float*)d_in[1];
    const float* pmem = (const float*)d_in[2];
    const float* awc  = (const float*)d_in[3];
    const unsigned char* mask = (const unsigned char*)d_in[4];
    const float* Wq   = (const float*)d_in[5];
    const float* Wcv  = (const float*)d_in[6];
    const float* Wloc = (const float*)d_in[7];
    const float* Wv   = (const float*)d_in[8];

    float* out = (float*)d_out;
    float* ctx = out;             // [B][EMB]
    float* wts = out + BB * EMB;  // [B][T]

    float* ws = (float*)d_ws;
    float* pq = ws;                 // [B][ATTN]
    float* wp = pq + BB * ATTN;     // [B][T]
    float* ms = wp + BB * TT;       // [B][NCH][2]
    float* cp = ms + BB * NCH * 2;  // [B][NCH][EMB]

    pq_kernel<<<BB * 4, 256, 0, stream>>>(h, Wq, pq);
    fused_kernel<<<BB * 32, 256, 0, stream>>>(pmem, awc, mem, mask, pq, Wcv,
                                              Wloc, Wv, wp, ms, cp);
    combine_kernel<<<BB, 256, 0, stream>>>(wp, ms, cp, ctx, wts);
}

// Round 6
// 186.384 us; speedup vs baseline: 1.7276x; 1.7276x over previous
//
#include <hip/hip_runtime.h>
#include <math.h>

#define BB 64
#define TT 2048
#define RNN 1024
#define EMB 512
#define ATTN 128
#define NF 32
#define KS 31
#define PADW 15

#define CHW 16            // t per wave
#define NCH (TT / CHW)    // 128 chunks per b
#define BLK_T 64          // t per block (4 waves)

__device__ __forceinline__ float fast_tanh(float x) {
    float ax = fabsf(x);
    float e = __expf(-2.f * ax);
    float r = (1.f - e) * __builtin_amdgcn_rcpf(1.f + e);
    return copysignf(r, x);
}

// ---------------------------------------------------------------------------
// Kernel 1: pq[b][a] = sum_r h[b][r] * Wq[a][r]
// ---------------------------------------------------------------------------
__global__ __launch_bounds__(256) void pq_kernel(const float* __restrict__ h,
                                                 const float* __restrict__ Wq,
                                                 float* __restrict__ pq) {
    int b = blockIdx.x >> 2;
    int q = blockIdx.x & 3;
    __shared__ float s_h[RNN];
    for (int i = threadIdx.x; i < RNN; i += 256) s_h[i] = h[b * RNN + i];
    __syncthreads();

    int wave = threadIdx.x >> 6;
    int lane = threadIdx.x & 63;
#pragma unroll 2
    for (int j = 0; j < 8; ++j) {
        int a = q * 32 + wave * 8 + j;
        const float4* wq4 = (const float4*)(Wq + (size_t)a * RNN);
        float acc = 0.f;
#pragma unroll
        for (int i = 0; i < 4; ++i) {
            float4 w4 = wq4[lane + 64 * i];
            float4 h4 = *(const float4*)(s_h + 4 * (lane + 64 * i));
            acc += w4.x * h4.x + w4.y * h4.y + w4.z * h4.z + w4.w * h4.w;
        }
#pragma unroll
        for (int off = 32; off > 0; off >>= 1) acc += __shfl_xor(acc, off, 64);
        if (lane == 0) pq[b * ATTN + a] = acc;
    }
}

// ---------------------------------------------------------------------------
// Kernel 2 (fused, one barrier): block = 64 t (4 waves), wave owns 16 t.
//   [stage awc + block conv] -> barrier -> per wave, no further sync:
//   energies (batched butterfly) -> in-register chunk softmax -> partial ctx
// grid = B * 32 = 2048, block = 256
// NOTE: no min-waves clamp — R5's (256,4) forced VGPR=64 and spilled ~550 MB
// of scratch traffic to HBM (WRITE_SIZE 445 MB vs 18 MB expected).
// ---------------------------------------------------------------------------
__global__ __launch_bounds__(256) void fused_kernel(
    const float* __restrict__ pm,     // [B][T][ATTN]
    const float* __restrict__ awc,    // [B][2][T]
    const float* __restrict__ mem,    // [B][T][EMB]
    const unsigned char* __restrict__ mask,  // [B][T]
    const float* __restrict__ pq,     // [B][ATTN]
    const float* __restrict__ Wconv,  // [NF][2][KS]
    const float* __restrict__ Wloc,   // [ATTN][NF]
    const float* __restrict__ Wv,     // [ATTN]
    float* __restrict__ wp,           // [B][T] unnormalized exp
    float* __restrict__ ms,           // [B][NCH][2] (m, s)
    float* __restrict__ cp)           // [B][NCH][EMB] partial ctx
{
    int b = blockIdx.x >> 5;
    int chg = blockIdx.x & 31;
    int t0b = chg * BLK_T;
    int tid = threadIdx.x;
    int w = tid >> 6;
    int lane = tid & 63;
    int ch = chg * 4 + w;        // wave's global chunk
    int t0w = ch * CHW;          // wave's first t

    __shared__ float s_awc[2][BLK_T + 2 * PADW + 2];  // 2 x 96
    __shared__ float s_conv[BLK_T][36];

    // ---- stage awc window for the block's 64 t ----
    for (int i = tid; i < 2 * (BLK_T + 2 * PADW); i += 256) {
        int c = i / (BLK_T + 2 * PADW);
        int j = i % (BLK_T + 2 * PADW);
        int tg = t0b - PADW + j;
        s_awc[c][j] = (tg >= 0 && tg < TT) ? awc[((size_t)b * 2 + c) * TT + tg] : 0.f;
    }
    __syncthreads();

    // ---- block-cooperative conv: t = tid&63, wave-uniform filter group ----
    {
        int t = tid & 63;
        float aw[2][KS];
#pragma unroll
        for (int c = 0; c < 2; ++c)
#pragma unroll
            for (int k = 0; k < KS; ++k) aw[c][k] = s_awc[c][t + k];
#pragma unroll
        for (int ff = 0; ff < 8; ++ff) {
            int f = w * 8 + ff;  // wave-uniform -> scalar Wconv loads
            float acc = 0.f;
#pragma unroll
            for (int c = 0; c < 2; ++c)
#pragma unroll
                for (int k = 0; k < KS; ++k)
                    acc += aw[c][k] * Wconv[(f * 2 + c) * KS + k];
            s_conv[t][f] = acc;
        }
    }
    __syncthreads();   // the ONLY barrier; all below is wave-autonomous

    // ---- energies: lane owns attn dims (lane, lane+64), 16 t in regs ----
    float wl0[NF], wl1[NF];
#pragma unroll
    for (int f = 0; f < NF; ++f) {
        wl0[f] = Wloc[lane * NF + f];
        wl1[f] = Wloc[(lane + 64) * NF + f];
    }
    float pq0 = pq[b * ATTN + lane], pq1 = pq[b * ATTN + lane + 64];
    float wv0 = Wv[lane], wv1 = Wv[lane + 64];

    float e[CHW];
#pragma unroll
    for (int h = 0; h < 2; ++h) {
        float pA[8], pB[8];
#pragma unroll
        for (int i = 0; i < 8; ++i) {  // issue 16 loads up front
            const float* r = pm + ((size_t)b * TT + t0w + h * 8 + i) * ATTN;
            pA[i] = r[lane];
            pB[i] = r[lane + 64];
        }
#pragma unroll
        for (int i = 0; i < 8; ++i) {
            int tl = w * CHW + h * 8 + i;   // row in s_conv
            float v0 = pq0 + pA[i], v1 = pq1 + pB[i];
            const float4* cv4 = (const float4*)&s_conv[tl][0];  // broadcast
#pragma unroll
            for (int f4 = 0; f4 < 8; ++f4) {
                float4 cv = cv4[f4];
                v0 += cv.x * wl0[f4 * 4 + 0] + cv.y * wl0[f4 * 4 + 1] +
                      cv.z * wl0[f4 * 4 + 2] + cv.w * wl0[f4 * 4 + 3];
                v1 += cv.x * wl1[f4 * 4 + 0] + cv.y * wl1[f4 * 4 + 1] +
                      cv.z * wl1[f4 * 4 + 2] + cv.w * wl1[f4 * 4 + 3];
            }
            e[h * 8 + i] = wv0 * fast_tanh(v0) + wv1 * fast_tanh(v1);
        }
    }

    // batched butterfly: 6 rounds x 16 independent shuffles
#pragma unroll
    for (int off = 32; off > 0; off >>= 1)
#pragma unroll
        for (int i = 0; i < CHW; ++i) e[i] += __shfl_xor(e[i], off, 64);
    // now every lane holds all 16 full energies

    // mask (broadcast word loads, applied uniformly in every lane)
    {
        const unsigned int* mk4 = (const unsigned int*)(mask + (size_t)b * TT + t0w);
#pragma unroll
        for (int q = 0; q < 4; ++q) {
            unsigned int mword = mk4[q];
#pragma unroll
            for (int j = 0; j < 4; ++j)
                if ((mword >> (8 * j)) & 0xff) e[q * 4 + j] = -1e30f;
        }
    }

    // in-register chunk softmax (redundant per lane; zero shuffles/LDS)
    float m = e[0];
#pragma unroll
    for (int i = 1; i < CHW; ++i) m = fmaxf(m, e[i]);
    float p[CHW], s = 0.f;
#pragma unroll
    for (int i = 0; i < CHW; ++i) {
        p[i] = __expf(e[i] - m);
        s += p[i];
    }
    if (lane == 0) {
        ms[((size_t)b * NCH + ch) * 2 + 0] = m;
        ms[((size_t)b * NCH + ch) * 2 + 1] = s;
    }
    // wp: lane i (<16) stores p[i] via cndmask select chain
    {
        float pv = p[0];
#pragma unroll
        for (int i = 1; i < CHW; ++i)
            if (lane == i) pv = p[i];
        if (lane < CHW) wp[(size_t)b * TT + t0w + lane] = pv;
    }

    // ---- partial ctx over wave's 16 t: lane owns float4 cols l, l+64 ----
    float4 a0 = {0.f, 0.f, 0.f, 0.f}, a1 = {0.f, 0.f, 0.f, 0.f};
    const float4* m4 = (const float4*)(mem + ((size_t)b * TT + t0w) * EMB);
#pragma unroll
    for (int i = 0; i < CHW; ++i) {
        float pi = p[i];
        float4 v0 = m4[(size_t)i * (EMB / 4) + lane];
        float4 v1 = m4[(size_t)i * (EMB / 4) + 64 + lane];
        a0.x += pi * v0.x; a0.y += pi * v0.y; a0.z += pi * v0.z; a0.w += pi * v0.w;
        a1.x += pi * v1.x; a1.y += pi * v1.y; a1.z += pi * v1.z; a1.w += pi * v1.w;
    }
    float4* cp4 = (float4*)(cp + ((size_t)b * NCH + ch) * EMB);
    cp4[lane] = a0;
    cp4[64 + lane] = a1;
}

// ---------------------------------------------------------------------------
// Kernel 3: combine. grid = B, block = 256.
// ---------------------------------------------------------------------------
__global__ __launch_bounds__(256) void combine_kernel(
    const float* __restrict__ wp, const float* __restrict__ ms,
    const float* __restrict__ cp, float* __restrict__ ctx,
    float* __restrict__ wts) {
    int b = blockIdx.x;
    int tid = threadIdx.x;
    __shared__ float s_m[NCH], s_s[NCH], s_scale[NCH];
    if (tid < NCH) {
        s_m[tid] = ms[((size_t)b * NCH + tid) * 2 + 0];
        s_s[tid] = ms[((size_t)b * NCH + tid) * 2 + 1];
    }
    __syncthreads();
    float M = -1e30f;
#pragma unroll 8
    for (int c = 0; c < NCH; ++c) M = fmaxf(M, s_m[c]);
    float S = 0.f;
#pragma unroll 8
    for (int c = 0; c < NCH; ++c) S += s_s[c] * __expf(s_m[c] - M);
    float invS = 1.f / S;
    if (tid < NCH) s_scale[tid] = __expf(s_m[tid] - M) * invS;
    __syncthreads();

    // ctx: 256 threads x float2 covers EMB=512
    {
        float2 acc = {0.f, 0.f};
        const float2* cp2 = (const float2*)(cp + (size_t)b * NCH * EMB);
#pragma unroll 4
        for (int c = 0; c < NCH; ++c) {
            float sc = s_scale[c];
            float2 v = cp2[(size_t)c * (EMB / 2) + tid];
            acc.x += sc * v.x;
            acc.y += sc * v.y;
        }
        ((float2*)(ctx + (size_t)b * EMB))[tid] = acc;
    }
#pragma unroll
    for (int i = 0; i < 8; ++i) {
        int t = i * 256 + tid;
        wts[(size_t)b * TT + t] = wp[(size_t)b * TT + t] * s_scale[t >> 4];
    }
}

// ---------------------------------------------------------------------------
extern "C" void kernel_launch(void* const* d_in, const int* in_sizes, int n_in,
                              void* d_out, int out_size, void* d_ws, size_t ws_size,
                              hipStream_t stream) {
    const float* h    = (const float*)d_in[0];
    const float* mem  = (const float*)d_in[1];
    const float* pmem = (const float*)d_in[2];
    const float* awc  = (const float*)d_in[3];
    const unsigned char* mask = (const unsigned char*)d_in[4];
    const float* Wq   = (const float*)d_in[5];
    const float* Wcv  = (const float*)d_in[6];
    const float* Wloc = (const float*)d_in[7];
    const float* Wv   = (const float*)d_in[8];

    float* out = (float*)d_out;
    float* ctx = out;             // [B][EMB]
    float* wts = out + BB * EMB;  // [B][T]

    float* ws = (float*)d_ws;
    float* pq = ws;                 // [B][ATTN]
    float* wp = pq + BB * ATTN;     // [B][T]
    float* ms = wp + BB * TT;       // [B][NCH][2]
    float* cp = ms + BB * NCH * 2;  // [B][NCH][EMB]

    pq_kernel<<<BB * 4, 256, 0, stream>>>(h, Wq, pq);
    fused_kernel<<<BB * 32, 256, 0, stream>>>(pmem, awc, mem, mask, pq, Wcv,
                                              Wloc, Wv, wp, ms, cp);
    combine_kernel<<<BB, 256, 0, stream>>>(wp, ms, cp, ctx, wts);
}